// Round 4
// baseline (524.087 us; speedup 1.0000x reference)
//
#include <hip/hip_runtime.h>

// (B,S,E,L) = (4, 4096, 64, 3)
#define SEQ  4096
#define EMB  64
#define NB   4
#define XROW 4097

// XOR swizzle for [row][64] bf16 tiles accessed as 16B chunks (chunk = 8 shorts).
// Row stride is 128 B == 32 banks, so bank index must come from the chunk bits:
// spread chunks across the 8 slots by XORing with row&7.  Apply on BOTH sides.
#define SW(r, c) ((r) * 64 + (((c) ^ ((r) & 7)) << 3))

typedef unsigned short ushort_t;
typedef __attribute__((ext_vector_type(8))) short short8;
typedef __attribute__((ext_vector_type(4))) float floatx4;

union U8 { uint4 u; short8 s8; };

// fp32 -> bf16 round-to-nearest-even
__device__ __forceinline__ ushort_t f2bf(float f) {
    union { float f; unsigned int u; } v; v.f = f;
    unsigned int r = v.u + 0x7FFFu + ((v.u >> 16) & 1u);
    return (ushort_t)(r >> 16);
}
__device__ __forceinline__ uint2 pack4bf(float a, float b, float c, float d) {
    uint2 p;
    p.x = (unsigned)f2bf(a) | ((unsigned)f2bf(b) << 16);
    p.y = (unsigned)f2bf(c) | ((unsigned)f2bf(d) << 16);
    return p;
}

// ---------------------------------------------------------------------------
// prep: rmT[e][f] = bf16(rm[f][e]) for e<63, 0 for e==63.  [64][4096] bf16
// Also initializes out[b] = offset (runs first in the stream).
// ---------------------------------------------------------------------------
__global__ __launch_bounds__(256) void prep_rmt(const float* __restrict__ rm,
                                                ushort_t* __restrict__ rmT,
                                                float* __restrict__ out,
                                                const float* __restrict__ offset) {
    if (blockIdx.x == 0 && threadIdx.x < NB) out[threadIdx.x] = offset[0];
    int o = (blockIdx.x * 256 + threadIdx.x) * 4;
    int e = o >> 12;
    int f = o & 4095;
    alignas(8) ushort_t t[4];
    t[0] = f2bf((e < 63) ? rm[(size_t)(f + 0) * 63 + e] : 0.f);
    t[1] = f2bf((e < 63) ? rm[(size_t)(f + 1) * 63 + e] : 0.f);
    t[2] = f2bf((e < 63) ? rm[(size_t)(f + 2) * 63 + e] : 0.f);
    t[3] = f2bf((e < 63) ? rm[(size_t)(f + 3) * 63 + e] : 0.f);
    *(uint2*)&rmT[o] = *(uint2*)t;
}

// ---------------------------------------------------------------------------
// Projection via MFMA, 512 threads: two wave-groups split the K range
// (2048 each), private LDS buffers, partial accumulators combined via LDS.
// av[row][e] = sum_f x[row][f]*rm[f][e] (e<63), av[row][63] = x[row][4096].
// ---------------------------------------------------------------------------
__global__ __launch_bounds__(512) void proj_mfma(const float* __restrict__ x,
        const ushort_t* __restrict__ rmT, float* __restrict__ av) {
    __shared__ ushort_t xs[2][64 * 64];   // per-half [row][f] bf16 (swizzled)
    __shared__ ushort_t rs[2][64 * 64];   // per-half [e][f]   bf16 (swizzled)
    const int tid = threadIdx.x;
    const int row0 = blockIdx.x * 64;
    const int w = tid >> 6, l = tid & 63;
    const int wg = w >> 2;                 // K-half (0/1)
    const int wq = w & 3;                  // m-subtile within half
    const int t4 = tid & 255;
    const int srow = t4 >> 2, sc = (t4 & 3) * 16;
    const int c0 = (t4 & 3) * 2;           // chunk index of this thread's 16B pair
    const int kbase = wg * 2048;
    const int quad = l >> 4, q16 = l & 15;

    floatx4 acc[4];
    #pragma unroll
    for (int i = 0; i < 4; ++i) acc[i] = (floatx4){0.f, 0.f, 0.f, 0.f};

    // prefetch tile 0 of this half
    float px[16];
    short8 pr0, pr1;
    {
        const float* xp = x + (size_t)(row0 + srow) * XROW + kbase + sc;
        #pragma unroll
        for (int i = 0; i < 16; ++i) px[i] = xp[i];
        const ushort_t* rp = rmT + (size_t)srow * SEQ + kbase + sc;
        pr0 = *(const short8*)&rp[0];
        pr1 = *(const short8*)&rp[8];
    }

    for (int k0 = 0; k0 < 2048; k0 += 64) {
        __syncthreads();
        {
            alignas(16) ushort_t tmp[16];
            #pragma unroll
            for (int i = 0; i < 16; ++i) tmp[i] = f2bf(px[i]);
            *(short8*)&xs[wg][SW(srow, c0)]     = *(short8*)&tmp[0];
            *(short8*)&xs[wg][SW(srow, c0 + 1)] = *(short8*)&tmp[8];
            *(short8*)&rs[wg][SW(srow, c0)]     = pr0;
            *(short8*)&rs[wg][SW(srow, c0 + 1)] = pr1;
        }
        __syncthreads();
        if (k0 + 64 < 2048) {   // prefetch next tile during compute
            const float* xp = x + (size_t)(row0 + srow) * XROW + kbase + k0 + 64 + sc;
            #pragma unroll
            for (int i = 0; i < 16; ++i) px[i] = xp[i];
            const ushort_t* rp = rmT + (size_t)srow * SEQ + kbase + k0 + 64 + sc;
            pr0 = *(const short8*)&rp[0];
            pr1 = *(const short8*)&rp[8];
        }
        #pragma unroll
        for (int ksp = 0; ksp < 2; ++ksp) {
            short8 a = *(short8*)&xs[wg][SW(wq * 16 + q16, ksp * 4 + quad)];
            #pragma unroll
            for (int nt = 0; nt < 4; ++nt) {
                short8 bf = *(short8*)&rs[wg][SW(nt * 16 + q16, ksp * 4 + quad)];
                acc[nt] = __builtin_amdgcn_mfma_f32_16x16x32_bf16(a, bf, acc[nt], 0, 0, 0);
            }
        }
    }

    // combine halves: half1 -> LDS (alias xs region), half0 adds + writes
    __syncthreads();
    float* poc = (float*)xs;   // 64*64 fp32 = 16 KB
    if (wg == 1) {
        #pragma unroll
        for (int nt = 0; nt < 4; ++nt)
            #pragma unroll
            for (int r = 0; r < 4; ++r)
                poc[(wq * 16 + quad * 4 + r) * 64 + nt * 16 + q16] = acc[nt][r];
    }
    __syncthreads();
    if (wg == 0) {
        #pragma unroll
        for (int nt = 0; nt < 4; ++nt)
            #pragma unroll
            for (int r = 0; r < 4; ++r) {
                int row = row0 + wq * 16 + quad * 4 + r;
                int col = nt * 16 + q16;
                float v = acc[nt][r] + poc[(wq * 16 + quad * 4 + r) * 64 + col];
                if (col == 63) v = x[(size_t)row * XROW + SEQ];
                av[(size_t)row * EMB + col] = v;
            }
    }
}

// ---------------------------------------------------------------------------
// qkv via MFMA: Qb/Kb bf16 [b][s][64], Vt bf16 [b][64][4096].
// 64 rows/block, 4 waves x 16 rows; weights staged transposed in LDS.
// ---------------------------------------------------------------------------
__global__ __launch_bounds__(256) void qkv_mfma(const float* __restrict__ av,
        const float* __restrict__ qw, const float* __restrict__ kw,
        const float* __restrict__ vw, ushort_t* __restrict__ Qb,
        ushort_t* __restrict__ Kb, ushort_t* __restrict__ Vt) {
    __shared__ ushort_t avs[64 * 64];
    __shared__ ushort_t wqs[64 * 64], wks[64 * 64], wvs[64 * 64];  // [e_out][k]
    const int tid = threadIdx.x;
    const int row0 = blockIdx.x * 64;
    const int w = tid >> 6, l = tid & 63;
    const int srow = tid >> 2, sc = (tid & 3) * 16;
    const int c0 = (tid & 3) * 2;

    {
        const float* ap = av + (size_t)(row0 + srow) * EMB + sc;
        alignas(16) ushort_t tmp[16];
        #pragma unroll
        for (int i = 0; i < 16; ++i) tmp[i] = f2bf(ap[i]);
        *(short8*)&avs[SW(srow, c0)]     = *(short8*)&tmp[0];
        *(short8*)&avs[SW(srow, c0 + 1)] = *(short8*)&tmp[8];
    }
    {
        alignas(16) ushort_t tq[16], tk[16], tv[16];
        #pragma unroll
        for (int i = 0; i < 16; ++i) {
            int kk = sc + i;
            tq[i] = f2bf(qw[kk * 64 + srow]);
            tk[i] = f2bf(kw[kk * 64 + srow]);
            tv[i] = f2bf(vw[kk * 64 + srow]);
        }
        *(short8*)&wqs[SW(srow, c0)]     = *(short8*)&tq[0];
        *(short8*)&wqs[SW(srow, c0 + 1)] = *(short8*)&tq[8];
        *(short8*)&wks[SW(srow, c0)]     = *(short8*)&tk[0];
        *(short8*)&wks[SW(srow, c0 + 1)] = *(short8*)&tk[8];
        *(short8*)&wvs[SW(srow, c0)]     = *(short8*)&tv[0];
        *(short8*)&wvs[SW(srow, c0 + 1)] = *(short8*)&tv[8];
    }
    __syncthreads();

    floatx4 aq[4], ak[4], avv[4];
    #pragma unroll
    for (int i = 0; i < 4; ++i) {
        aq[i] = (floatx4){0.f, 0.f, 0.f, 0.f};
        ak[i] = aq[i]; avv[i] = aq[i];
    }
    #pragma unroll
    for (int ksp = 0; ksp < 2; ++ksp) {
        short8 a = *(short8*)&avs[SW(w * 16 + (l & 15), ksp * 4 + (l >> 4))];
        #pragma unroll
        for (int nt = 0; nt < 4; ++nt) {
            int bo = SW(nt * 16 + (l & 15), ksp * 4 + (l >> 4));
            aq[nt]  = __builtin_amdgcn_mfma_f32_16x16x32_bf16(a, *(short8*)&wqs[bo], aq[nt], 0, 0, 0);
            ak[nt]  = __builtin_amdgcn_mfma_f32_16x16x32_bf16(a, *(short8*)&wks[bo], ak[nt], 0, 0, 0);
            avv[nt] = __builtin_amdgcn_mfma_f32_16x16x32_bf16(a, *(short8*)&wvs[bo], avv[nt], 0, 0, 0);
        }
    }

    const int b = row0 >> 12;
    #pragma unroll
    for (int nt = 0; nt < 4; ++nt)
        #pragma unroll
        for (int r = 0; r < 4; ++r) {
            int row = row0 + w * 16 + (l >> 4) * 4 + r;
            int col = nt * 16 + (l & 15);
            size_t o = (size_t)row * EMB + col;
            Qb[o] = f2bf(aq[nt][r]);
            Kb[o] = f2bf(ak[nt][r]);
            Vt[((size_t)b * EMB + col) * SEQ + (row & 4095)] = f2bf(avv[nt][r]);
        }
}

// ---------------------------------------------------------------------------
// MFMA flash attention, S^T form, no-max streaming softmax.
// 512 threads = 8 waves = 4 k-quarters (wg) x 2 q-halves (wq, 32 rows each).
// K/V staged in LDS (swizzled); each fragment read feeds 2 MFMAs (2 q-halves).
// XCD-aware block remap: each XCD serves exactly one batch (KV 1 MB/L2).
// V-fragments hoisted before exp/pack; setprio(1) around MFMA clusters.
// ---------------------------------------------------------------------------
__global__ __launch_bounds__(512) void flash_mfma(const ushort_t* __restrict__ Qb,
        const ushort_t* __restrict__ Kb, const ushort_t* __restrict__ Vt,
        float* __restrict__ out) {
    __shared__ ushort_t ks[4][64 * 64];     // per-quarter [kr][e] (swizzled) 32 KB
    __shared__ ushort_t vt[4][64 * 64];     // per-quarter [e][kr] (swizzled) 32 KB
    __shared__ ushort_t psbuf[8 * 2048];    // per-wave 2 qh x 1024 (4 KB/wave) 32 KB
    __shared__ float comb[3][64 * 64];      // k-partials of wg=1..3 (48 KB)
    __shared__ float lrow[4][64];
    const int tid = threadIdx.x;
    const int w = tid >> 6, l = tid & 63;
    const int wg = w >> 1;                  // k-quarter 0..3
    const int wq = w & 1;                   // q-half (32 rows)
    const int quad = l >> 4, q16 = l & 15;
    // XCD-aware bijective remap: dispatch id flat = x + 64*y round-robins
    // XCDs as flat&7.  Give XCD x the batch x>>1 -> per-L2 KV = 1 MB.
    const int flat = blockIdx.y * 64 + blockIdx.x;
    const int xcd = flat & 7, slot = flat >> 3;
    const int b = xcd >> 1;
    const int q0 = ((xcd & 1) * 32 + slot) * 64;
    const size_t base  = (size_t)b * SEQ * EMB;
    const size_t vbase = (size_t)b * EMB * SEQ;
    // staging assignment: 128 threads per quarter, 2 threads per row,
    // each thread 4 consecutive 16B chunks (64 B contiguous global)
    const int qtr  = tid >> 7;              // staging quarter 0..3
    const int t7   = tid & 127;
    const int srow = t7 >> 1;               // 0..63
    const int hc   = (t7 & 1) * 4;          // chunk base 0 or 4
    ushort_t* ps = &psbuf[w * 2048];

    // Q fragments: lane q16 holds row q0+wq*32+qh*16+q16, 8 e per ksp
    short8 qf[2][2];
    #pragma unroll
    for (int qh = 0; qh < 2; ++qh)
        #pragma unroll
        for (int ksp = 0; ksp < 2; ++ksp)
            qf[qh][ksp] = *(const short8*)&Qb[base
                + (size_t)(q0 + wq * 32 + qh * 16 + q16) * EMB + ksp * 32 + quad * 8];

    // prefetch tile 0 of this thread's staging quarter
    short8 pk[4], pv[4];
    {
        const ushort_t* kp = Kb + base + (size_t)(qtr * 1024 + srow) * EMB + hc * 8;
        const ushort_t* vp = Vt + vbase + (size_t)srow * SEQ + qtr * 1024 + hc * 8;
        #pragma unroll
        for (int j = 0; j < 4; ++j) {
            pk[j] = *(const short8*)(kp + j * 8);
            pv[j] = *(const short8*)(vp + j * 8);
        }
    }

    floatx4 o_acc[2][4];
    #pragma unroll
    for (int qh = 0; qh < 2; ++qh)
        #pragma unroll
        for (int i = 0; i < 4; ++i) o_acc[qh][i] = (floatx4){0.f, 0.f, 0.f, 0.f};
    float lp0 = 0.f, lp1 = 0.f;

    for (int kt0 = 0; kt0 < 1024; kt0 += 64) {
        __syncthreads();
        #pragma unroll
        for (int j = 0; j < 4; ++j) {
            *(short8*)&ks[qtr][SW(srow, hc + j)] = pk[j];
            *(short8*)&vt[qtr][SW(srow, hc + j)] = pv[j];
        }
        __syncthreads();
        if (kt0 + 64 < 1024) {   // prefetch next tile during compute
            const ushort_t* kp = Kb + base + (size_t)(qtr * 1024 + kt0 + 64 + srow) * EMB + hc * 8;
            const ushort_t* vp = Vt + vbase + (size_t)srow * SEQ + qtr * 1024 + kt0 + 64 + hc * 8;
            #pragma unroll
            for (int j = 0; j < 4; ++j) {
                pk[j] = *(const short8*)(kp + j * 8);
                pv[j] = *(const short8*)(vp + j * 8);
            }
        }

        // S^T = K Q^T : A = K fragment from LDS, shared across both q-halves
        floatx4 s[2][4];
        #pragma unroll
        for (int qh = 0; qh < 2; ++qh)
            #pragma unroll
            for (int nt = 0; nt < 4; ++nt) s[qh][nt] = (floatx4){0.f, 0.f, 0.f, 0.f};
        __builtin_amdgcn_s_setprio(1);
        #pragma unroll
        for (int ksp = 0; ksp < 2; ++ksp) {
            #pragma unroll
            for (int nt = 0; nt < 4; ++nt) {
                short8 a = *(short8*)&ks[wg][SW(nt * 16 + q16, ksp * 4 + quad)];
                s[0][nt] = __builtin_amdgcn_mfma_f32_16x16x32_bf16(a, qf[0][ksp], s[0][nt], 0, 0, 0);
                s[1][nt] = __builtin_amdgcn_mfma_f32_16x16x32_bf16(a, qf[1][ksp], s[1][nt], 0, 0, 0);
            }
        }
        __builtin_amdgcn_s_setprio(0);

        // V fragments issued EARLY: their LDS latency hides under exp/pack
        short8 bv[2][4];
        #pragma unroll
        for (int ksp = 0; ksp < 2; ++ksp)
            #pragma unroll
            for (int nt = 0; nt < 4; ++nt)
                bv[ksp][nt] = *(short8*)&vt[wg][SW(nt * 16 + q16, ksp * 4 + quad)];

        // exp + pack -> wave-local swizzled P buffer (no barrier needed)
        #pragma unroll
        for (int nt = 0; nt < 4; ++nt) {
            float p0 = __expf(s[0][nt][0]);
            float p1 = __expf(s[0][nt][1]);
            float p2 = __expf(s[0][nt][2]);
            float p3 = __expf(s[0][nt][3]);
            lp0 += (p0 + p1) + (p2 + p3);
            int g = nt * 4 + quad;
            *(uint2*)&ps[q16 * 64 + ((g ^ q16) & 15) * 4] = pack4bf(p0, p1, p2, p3);
        }
        #pragma unroll
        for (int nt = 0; nt < 4; ++nt) {
            float p0 = __expf(s[1][nt][0]);
            float p1 = __expf(s[1][nt][1]);
            float p2 = __expf(s[1][nt][2]);
            float p3 = __expf(s[1][nt][3]);
            lp1 += (p0 + p1) + (p2 + p3);
            int g = nt * 4 + quad;
            *(uint2*)&ps[1024 + q16 * 64 + ((g ^ q16) & 15) * 4] = pack4bf(p0, p1, p2, p3);
        }
        asm volatile("s_waitcnt lgkmcnt(0)" ::: "memory");

        // O += P V : B = V fragment (pre-loaded), A = P from wave-local LDS
        __builtin_amdgcn_s_setprio(1);
        #pragma unroll
        for (int ksp = 0; ksp < 2; ++ksp) {
            #pragma unroll
            for (int qh = 0; qh < 2; ++qh) {
                int g0 = ksp * 8 + quad * 2;
                uint2 a0 = *(uint2*)&ps[qh * 1024 + q16 * 64 + ((g0 ^ q16) & 15) * 4];
                uint2 a1 = *(uint2*)&ps[qh * 1024 + q16 * 64 + (((g0 + 1) ^ q16) & 15) * 4];
                U8 af;
                af.u.x = a0.x; af.u.y = a0.y; af.u.z = a1.x; af.u.w = a1.y;
                #pragma unroll
                for (int nt = 0; nt < 4; ++nt)
                    o_acc[qh][nt] = __builtin_amdgcn_mfma_f32_16x16x32_bf16(af.s8, bv[ksp][nt], o_acc[qh][nt], 0, 0, 0);
            }
        }
        __builtin_amdgcn_s_setprio(0);
    }

    // l: reduce over quads (lanes sharing q16)
    lp0 += __shfl_xor(lp0, 16);
    lp0 += __shfl_xor(lp0, 32);
    lp1 += __shfl_xor(lp1, 16);
    lp1 += __shfl_xor(lp1, 32);
    if (quad == 0) {
        lrow[wg][wq * 32 + q16]      = lp0;
        lrow[wg][wq * 32 + 16 + q16] = lp1;
    }
    if (wg > 0) {
        #pragma unroll
        for (int qh = 0; qh < 2; ++qh)
            #pragma unroll
            for (int nt = 0; nt < 4; ++nt)
                #pragma unroll
                for (int r = 0; r < 4; ++r)
                    comb[wg - 1][(wq * 32 + qh * 16 + quad * 4 + r) * 64 + nt * 16 + q16]
                        = o_acc[qh][nt][r];
    }
    __syncthreads();
    if (wg == 0) {
        #pragma unroll
        for (int qh = 0; qh < 2; ++qh) {
            float linv[4];
            #pragma unroll
            for (int r = 0; r < 4; ++r) {
                int ql = wq * 32 + qh * 16 + quad * 4 + r;
                linv[r] = 1.f / (lrow[0][ql] + lrow[1][ql] + lrow[2][ql] + lrow[3][ql]);
            }
            #pragma unroll
            for (int nt = 0; nt < 4; ++nt)
                #pragma unroll
                for (int r = 0; r < 4; ++r) {
                    int ql = wq * 32 + qh * 16 + quad * 4 + r;
                    int col = nt * 16 + q16;
                    float v = (o_acc[qh][nt][r] + comb[0][ql * 64 + col]
                               + comb[1][ql * 64 + col] + comb[2][ql * 64 + col]) * linv[r];
                    out[base + (size_t)(q0 + ql) * EMB + col] = v;
                }
        }
    }
}

// ---------------------------------------------------------------------------
// Final contraction: out[b] += sum av[b,s,e]*coeffs[s,e]  (out pre-init'd)
// 64 x-blocks per batch so the grid fills all 256 CUs.
// ---------------------------------------------------------------------------
__global__ __launch_bounds__(256) void reduce_kernel(const float* __restrict__ av,
        const float* __restrict__ coeffs, float* __restrict__ out) {
    const int b = blockIdx.y;
    const size_t base = (size_t)b * SEQ * EMB;
    const int local0 = blockIdx.x * 4096;    // 64 x-blocks x 4096 floats
    const int tid = threadIdx.x;
    float ssum = 0.f;
    #pragma unroll
    for (int i = 0; i < 4; ++i) {
        int idx = local0 + (tid + i * 256) * 4;
        float4 a = *(const float4*)&av[base + idx];
        float4 c = *(const float4*)&coeffs[idx];
        ssum += a.x * c.x + a.y * c.y + a.z * c.z + a.w * c.w;
    }
    #pragma unroll
    for (int off = 1; off < 64; off <<= 1) ssum += __shfl_xor(ssum, off);
    __shared__ float wsum[4];
    if ((tid & 63) == 0) wsum[tid >> 6] = ssum;
    __syncthreads();
    if (tid == 0)
        atomicAdd(&out[b], wsum[0] + wsum[1] + wsum[2] + wsum[3]);
}

// ---------------------------------------------------------------------------
extern "C" void kernel_launch(void* const* d_in, const int* in_sizes, int n_in,
                              void* d_out, int out_size, void* d_ws, size_t ws_size,
                              hipStream_t stream) {
    const float* x      = (const float*)d_in[0];
    const float* q_ws   = (const float*)d_in[1];
    const float* k_ws   = (const float*)d_in[2];
    const float* v_ws   = (const float*)d_in[3];
    const float* rm     = (const float*)d_in[4];
    const float* coeffs = (const float*)d_in[5];
    const float* offset = (const float*)d_in[6];
    float* out = (float*)d_out;
    char* ws = (char*)d_ws;

    float*    AV  = (float*)ws;                          // 4 MB fp32
    ushort_t* Qb  = (ushort_t*)(ws + 4 * 1024 * 1024);   // 2 MB bf16
    ushort_t* Kb  = (ushort_t*)(ws + 6 * 1024 * 1024);   // 2 MB bf16
    ushort_t* Vt  = (ushort_t*)(ws + 8 * 1024 * 1024);   // 2 MB bf16
    ushort_t* rmT = (ushort_t*)(ws + 10 * 1024 * 1024);  // 0.5 MB bf16

    prep_rmt<<<256, 256, 0, stream>>>(rm, rmT, out, offset);
    proj_mfma<<<256, 512, 0, stream>>>(x, rmT, AV);
    for (int layer = 0; layer < 3; ++layer) {
        qkv_mfma<<<256, 256, 0, stream>>>(AV, q_ws + layer * 4096,
                                          k_ws + layer * 4096, v_ws + layer * 4096,
                                          Qb, Kb, Vt);
        flash_mfma<<<dim3(64, NB), 512, 0, stream>>>(Qb, Kb, Vt, AV);
    }
    reduce_kernel<<<dim3(64, NB), 256, 0, stream>>>(AV, coeffs, out);
}

// Round 5
// 517.908 us; speedup vs baseline: 1.0119x; 1.0119x over previous
//
#include <hip/hip_runtime.h>

// (B,S,E,L) = (4, 4096, 64, 3)
#define SEQ  4096
#define EMB  64
#define NB   4
#define XROW 4097

// XOR swizzle for [row][64] bf16 tiles accessed as 16B chunks (chunk = 8 shorts).
#define SW(r, c)    ((r) * 64 + (((c) ^ ((r) & 7)) << 3))
// element-granular variant (row, column) for scalar writes into a SW-tiled buffer
#define SWE(r, col) ((r) * 64 + (((((col) >> 3)) ^ ((r) & 7)) << 3) + ((col) & 7))

typedef unsigned short ushort_t;
typedef __attribute__((ext_vector_type(8))) short short8;
typedef __attribute__((ext_vector_type(4))) float floatx4;

union U8 { uint4 u; short8 s8; };

// fp32 -> bf16 round-to-nearest-even
__device__ __forceinline__ ushort_t f2bf(float f) {
    union { float f; unsigned int u; } v; v.f = f;
    unsigned int r = v.u + 0x7FFFu + ((v.u >> 16) & 1u);
    return (ushort_t)(r >> 16);
}
__device__ __forceinline__ uint2 pack4bf(float a, float b, float c, float d) {
    uint2 p;
    p.x = (unsigned)f2bf(a) | ((unsigned)f2bf(b) << 16);
    p.y = (unsigned)f2bf(c) | ((unsigned)f2bf(d) << 16);
    return p;
}

// ---------------------------------------------------------------------------
// prep: rmT[e][f] = bf16(rm[f][e]) for e<63, 0 for e==63.  [64][4096] bf16
// Also initializes out[b] = offset (runs first in the stream).
// ---------------------------------------------------------------------------
__global__ __launch_bounds__(256) void prep_rmt(const float* __restrict__ rm,
                                                ushort_t* __restrict__ rmT,
                                                float* __restrict__ out,
                                                const float* __restrict__ offset) {
    if (blockIdx.x == 0 && threadIdx.x < NB) out[threadIdx.x] = offset[0];
    int o = (blockIdx.x * 256 + threadIdx.x) * 4;
    int e = o >> 12;
    int f = o & 4095;
    alignas(8) ushort_t t[4];
    t[0] = f2bf((e < 63) ? rm[(size_t)(f + 0) * 63 + e] : 0.f);
    t[1] = f2bf((e < 63) ? rm[(size_t)(f + 1) * 63 + e] : 0.f);
    t[2] = f2bf((e < 63) ? rm[(size_t)(f + 2) * 63 + e] : 0.f);
    t[3] = f2bf((e < 63) ? rm[(size_t)(f + 3) * 63 + e] : 0.f);
    *(uint2*)&rmT[o] = *(uint2*)t;
}

// ---------------------------------------------------------------------------
// Projection via MFMA + FUSED layer-0 QKV epilogue.
// Main loop identical to the verified proj_mfma.  Epilogue: stage av-tile
// (bf16, swizzled) + layer-0 weights in LDS, run the proven qkv MFMA mapping
// with all 8 waves, write Qb/Kb/Vt directly.  AV never touches global.
// ---------------------------------------------------------------------------
__global__ __launch_bounds__(512) void proj_qkv(const float* __restrict__ x,
        const ushort_t* __restrict__ rmT,
        const float* __restrict__ qw, const float* __restrict__ kw,
        const float* __restrict__ vw,
        ushort_t* __restrict__ Qo, ushort_t* __restrict__ Ko,
        ushort_t* __restrict__ Vo) {
    __shared__ ushort_t xs[2][64 * 64];   // loop: x tiles; epilogue: poc (fp32)
    __shared__ ushort_t rs[2][64 * 64];   // loop: rmT tiles; epilogue: wq, wk
    __shared__ ushort_t ep[2][64 * 64];   // epilogue: wv, O-tile
    const int tid = threadIdx.x;
    const int row0 = blockIdx.x * 64;
    const int w = tid >> 6, l = tid & 63;
    const int wg = w >> 2;                 // K-half (0/1)
    const int wq = w & 3;                  // m-subtile within half
    const int t4 = tid & 255;
    const int srow = t4 >> 2, sc = (t4 & 3) * 16;
    const int c0 = (t4 & 3) * 2;           // chunk index of this thread's 16B pair
    const int kbase = wg * 2048;
    const int quad = l >> 4, q16 = l & 15;

    floatx4 acc[4];
    #pragma unroll
    for (int i = 0; i < 4; ++i) acc[i] = (floatx4){0.f, 0.f, 0.f, 0.f};

    // prefetch tile 0 of this half
    float px[16];
    short8 pr0, pr1;
    {
        const float* xp = x + (size_t)(row0 + srow) * XROW + kbase + sc;
        #pragma unroll
        for (int i = 0; i < 16; ++i) px[i] = xp[i];
        const ushort_t* rp = rmT + (size_t)srow * SEQ + kbase + sc;
        pr0 = *(const short8*)&rp[0];
        pr1 = *(const short8*)&rp[8];
    }

    for (int k0 = 0; k0 < 2048; k0 += 64) {
        __syncthreads();
        {
            alignas(16) ushort_t tmp[16];
            #pragma unroll
            for (int i = 0; i < 16; ++i) tmp[i] = f2bf(px[i]);
            *(short8*)&xs[wg][SW(srow, c0)]     = *(short8*)&tmp[0];
            *(short8*)&xs[wg][SW(srow, c0 + 1)] = *(short8*)&tmp[8];
            *(short8*)&rs[wg][SW(srow, c0)]     = pr0;
            *(short8*)&rs[wg][SW(srow, c0 + 1)] = pr1;
        }
        __syncthreads();
        if (k0 + 64 < 2048) {   // prefetch next tile during compute
            const float* xp = x + (size_t)(row0 + srow) * XROW + kbase + k0 + 64 + sc;
            #pragma unroll
            for (int i = 0; i < 16; ++i) px[i] = xp[i];
            const ushort_t* rp = rmT + (size_t)srow * SEQ + kbase + k0 + 64 + sc;
            pr0 = *(const short8*)&rp[0];
            pr1 = *(const short8*)&rp[8];
        }
        #pragma unroll
        for (int ksp = 0; ksp < 2; ++ksp) {
            short8 a = *(short8*)&xs[wg][SW(wq * 16 + q16, ksp * 4 + quad)];
            #pragma unroll
            for (int nt = 0; nt < 4; ++nt) {
                short8 bf = *(short8*)&rs[wg][SW(nt * 16 + q16, ksp * 4 + quad)];
                acc[nt] = __builtin_amdgcn_mfma_f32_16x16x32_bf16(a, bf, acc[nt], 0, 0, 0);
            }
        }
    }

    // ---------------- fused epilogue ----------------
    __syncthreads();                       // everyone done with xs/rs
    float* poc = (float*)xs;               // 64*64 fp32 = 16 KB
    if (wg == 1) {
        #pragma unroll
        for (int nt = 0; nt < 4; ++nt)
            #pragma unroll
            for (int r = 0; r < 4; ++r)
                poc[(wq * 16 + quad * 4 + r) * 64 + nt * 16 + q16] = acc[nt][r];
    }
    // stage layer-0 weights transposed [e_out][k] (all 512 threads)
    {
        const int wrow = tid >> 3, wch = tid & 7;
        alignas(16) ushort_t tw[8];
        ushort_t* wdst[3] = { rs[0], rs[1], ep[0] };
        const float* wsrc[3] = { qw, kw, vw };
        #pragma unroll
        for (int m = 0; m < 3; ++m) {
            #pragma unroll
            for (int i = 0; i < 8; ++i)
                tw[i] = f2bf(wsrc[m][(wch * 8 + i) * 64 + wrow]);
            *(short8*)&wdst[m][SW(wrow, wch)] = *(short8*)tw;
        }
    }
    __syncthreads();
    ushort_t* ot = ep[1];
    if (wg == 0) {
        #pragma unroll
        for (int nt = 0; nt < 4; ++nt)
            #pragma unroll
            for (int r = 0; r < 4; ++r) {
                int ql = wq * 16 + quad * 4 + r;
                int col = nt * 16 + q16;
                float v = acc[nt][r] + poc[ql * 64 + col];
                if (col == 63) v = x[(size_t)(row0 + ql) * XROW + SEQ];
                ot[SWE(ql, col)] = f2bf(v);
            }
    }
    __syncthreads();
    // QKV: waves 0-3 compute Q,K for rows (w&3)*16; waves 4-7 compute V
    {
        const int erow = (w & 3) * 16;
        floatx4 ra[4], rb[4];
        #pragma unroll
        for (int i = 0; i < 4; ++i) {
            ra[i] = (floatx4){0.f, 0.f, 0.f, 0.f};
            rb[i] = ra[i];
        }
        const ushort_t* wb0 = (w < 4) ? rs[0] : ep[0];   // Q or V weights
        #pragma unroll
        for (int ksp = 0; ksp < 2; ++ksp) {
            short8 a = *(short8*)&ot[SW(erow + q16, ksp * 4 + quad)];
            #pragma unroll
            for (int nt = 0; nt < 4; ++nt) {
                int bo = SW(nt * 16 + q16, ksp * 4 + quad);
                ra[nt] = __builtin_amdgcn_mfma_f32_16x16x32_bf16(a, *(short8*)&wb0[bo], ra[nt], 0, 0, 0);
                if (w < 4)
                    rb[nt] = __builtin_amdgcn_mfma_f32_16x16x32_bf16(a, *(short8*)&rs[1][bo], rb[nt], 0, 0, 0);
            }
        }
        const int b = row0 >> 12;
        #pragma unroll
        for (int nt = 0; nt < 4; ++nt)
            #pragma unroll
            for (int r = 0; r < 4; ++r) {
                int row = row0 + erow + quad * 4 + r;
                int col = nt * 16 + q16;
                if (w < 4) {
                    Qo[(size_t)row * EMB + col] = f2bf(ra[nt][r]);
                    Ko[(size_t)row * EMB + col] = f2bf(rb[nt][r]);
                } else {
                    Vo[((size_t)b * EMB + col) * SEQ + (row & 4095)] = f2bf(ra[nt][r]);
                }
            }
    }
}

// ---------------------------------------------------------------------------
// MFMA flash attention (verified R3/R4 inner loop) + fused epilogue.
// MODE 0: epilogue applies next-layer QKV (writes Qo/Ko/Vo, double-buffered).
// MODE 1: epilogue contracts O with coeffs and atomicAdds into out[b].
// ---------------------------------------------------------------------------
template<int MODE>
__global__ __launch_bounds__(512) void flash_fused(const ushort_t* __restrict__ Qb,
        const ushort_t* __restrict__ Kb, const ushort_t* __restrict__ Vt,
        const float* __restrict__ qw, const float* __restrict__ kw,
        const float* __restrict__ vw,
        ushort_t* __restrict__ Qo, ushort_t* __restrict__ Ko,
        ushort_t* __restrict__ Vo,
        const float* __restrict__ coeffs, float* __restrict__ out) {
    __shared__ ushort_t ks[4][64 * 64];     // per-quarter [kr][e] (swizzled) 32 KB
    __shared__ ushort_t vt[4][64 * 64];     // per-quarter [e][kr] (swizzled) 32 KB
    __shared__ ushort_t psbuf[8 * 2048];    // loop: per-wave P; epilogue: weights+O
    __shared__ float comb[3][64 * 64];      // k-partials of wg=1..3 (48 KB)
    __shared__ float lrow[4][64];
    const int tid = threadIdx.x;
    const int w = tid >> 6, l = tid & 63;
    const int wg = w >> 1;                  // k-quarter 0..3
    const int wq = w & 1;                   // q-half (32 rows)
    const int quad = l >> 4, q16 = l & 15;
    // XCD-aware bijective remap: XCD x serves batch x>>1 only.
    const int flat = blockIdx.y * 64 + blockIdx.x;
    const int xcd = flat & 7, slot = flat >> 3;
    const int b = xcd >> 1;
    const int q0 = ((xcd & 1) * 32 + slot) * 64;
    const size_t base  = (size_t)b * SEQ * EMB;
    const size_t vbase = (size_t)b * EMB * SEQ;
    const int qtr  = tid >> 7;              // staging quarter 0..3
    const int t7   = tid & 127;
    const int srow = t7 >> 1;               // 0..63
    const int hc   = (t7 & 1) * 4;          // chunk base 0 or 4
    ushort_t* ps = &psbuf[w * 2048];

    // Q fragments
    short8 qf[2][2];
    #pragma unroll
    for (int qh = 0; qh < 2; ++qh)
        #pragma unroll
        for (int ksp = 0; ksp < 2; ++ksp)
            qf[qh][ksp] = *(const short8*)&Qb[base
                + (size_t)(q0 + wq * 32 + qh * 16 + q16) * EMB + ksp * 32 + quad * 8];

    // prefetch tile 0 of this thread's staging quarter
    short8 pk[4], pv[4];
    {
        const ushort_t* kp = Kb + base + (size_t)(qtr * 1024 + srow) * EMB + hc * 8;
        const ushort_t* vp = Vt + vbase + (size_t)srow * SEQ + qtr * 1024 + hc * 8;
        #pragma unroll
        for (int j = 0; j < 4; ++j) {
            pk[j] = *(const short8*)(kp + j * 8);
            pv[j] = *(const short8*)(vp + j * 8);
        }
    }

    floatx4 o_acc[2][4];
    #pragma unroll
    for (int qh = 0; qh < 2; ++qh)
        #pragma unroll
        for (int i = 0; i < 4; ++i) o_acc[qh][i] = (floatx4){0.f, 0.f, 0.f, 0.f};
    float lp0 = 0.f, lp1 = 0.f;

    for (int kt0 = 0; kt0 < 1024; kt0 += 64) {
        __syncthreads();
        #pragma unroll
        for (int j = 0; j < 4; ++j) {
            *(short8*)&ks[qtr][SW(srow, hc + j)] = pk[j];
            *(short8*)&vt[qtr][SW(srow, hc + j)] = pv[j];
        }
        __syncthreads();
        if (kt0 + 64 < 1024) {
            const ushort_t* kp = Kb + base + (size_t)(qtr * 1024 + kt0 + 64 + srow) * EMB + hc * 8;
            const ushort_t* vp = Vt + vbase + (size_t)srow * SEQ + qtr * 1024 + kt0 + 64 + hc * 8;
            #pragma unroll
            for (int j = 0; j < 4; ++j) {
                pk[j] = *(const short8*)(kp + j * 8);
                pv[j] = *(const short8*)(vp + j * 8);
            }
        }

        // S^T = K Q^T
        floatx4 s[2][4];
        #pragma unroll
        for (int qh = 0; qh < 2; ++qh)
            #pragma unroll
            for (int nt = 0; nt < 4; ++nt) s[qh][nt] = (floatx4){0.f, 0.f, 0.f, 0.f};
        __builtin_amdgcn_s_setprio(1);
        #pragma unroll
        for (int ksp = 0; ksp < 2; ++ksp) {
            #pragma unroll
            for (int nt = 0; nt < 4; ++nt) {
                short8 a = *(short8*)&ks[wg][SW(nt * 16 + q16, ksp * 4 + quad)];
                s[0][nt] = __builtin_amdgcn_mfma_f32_16x16x32_bf16(a, qf[0][ksp], s[0][nt], 0, 0, 0);
                s[1][nt] = __builtin_amdgcn_mfma_f32_16x16x32_bf16(a, qf[1][ksp], s[1][nt], 0, 0, 0);
            }
        }
        __builtin_amdgcn_s_setprio(0);

        // V fragments issued early
        short8 bv[2][4];
        #pragma unroll
        for (int ksp = 0; ksp < 2; ++ksp)
            #pragma unroll
            for (int nt = 0; nt < 4; ++nt)
                bv[ksp][nt] = *(short8*)&vt[wg][SW(nt * 16 + q16, ksp * 4 + quad)];

        // exp + pack -> wave-local swizzled P buffer
        #pragma unroll
        for (int nt = 0; nt < 4; ++nt) {
            float p0 = __expf(s[0][nt][0]);
            float p1 = __expf(s[0][nt][1]);
            float p2 = __expf(s[0][nt][2]);
            float p3 = __expf(s[0][nt][3]);
            lp0 += (p0 + p1) + (p2 + p3);
            int g = nt * 4 + quad;
            *(uint2*)&ps[q16 * 64 + ((g ^ q16) & 15) * 4] = pack4bf(p0, p1, p2, p3);
        }
        #pragma unroll
        for (int nt = 0; nt < 4; ++nt) {
            float p0 = __expf(s[1][nt][0]);
            float p1 = __expf(s[1][nt][1]);
            float p2 = __expf(s[1][nt][2]);
            float p3 = __expf(s[1][nt][3]);
            lp1 += (p0 + p1) + (p2 + p3);
            int g = nt * 4 + quad;
            *(uint2*)&ps[1024 + q16 * 64 + ((g ^ q16) & 15) * 4] = pack4bf(p0, p1, p2, p3);
        }
        asm volatile("s_waitcnt lgkmcnt(0)" ::: "memory");

        // O += P V
        __builtin_amdgcn_s_setprio(1);
        #pragma unroll
        for (int ksp = 0; ksp < 2; ++ksp) {
            #pragma unroll
            for (int qh = 0; qh < 2; ++qh) {
                int g0 = ksp * 8 + quad * 2;
                uint2 a0 = *(uint2*)&ps[qh * 1024 + q16 * 64 + ((g0 ^ q16) & 15) * 4];
                uint2 a1 = *(uint2*)&ps[qh * 1024 + q16 * 64 + (((g0 + 1) ^ q16) & 15) * 4];
                U8 af;
                af.u.x = a0.x; af.u.y = a0.y; af.u.z = a1.x; af.u.w = a1.y;
                #pragma unroll
                for (int nt = 0; nt < 4; ++nt)
                    o_acc[qh][nt] = __builtin_amdgcn_mfma_f32_16x16x32_bf16(af.s8, bv[ksp][nt], o_acc[qh][nt], 0, 0, 0);
            }
        }
        __builtin_amdgcn_s_setprio(0);
    }

    // ---------------- fused epilogue ----------------
    lp0 += __shfl_xor(lp0, 16);
    lp0 += __shfl_xor(lp0, 32);
    lp1 += __shfl_xor(lp1, 16);
    lp1 += __shfl_xor(lp1, 32);
    __syncthreads();                       // everyone done with ks/vt/psbuf loop use
    if (quad == 0) {
        lrow[wg][wq * 32 + q16]      = lp0;
        lrow[wg][wq * 32 + 16 + q16] = lp1;
    }
    if (wg > 0) {
        #pragma unroll
        for (int qh = 0; qh < 2; ++qh)
            #pragma unroll
            for (int nt = 0; nt < 4; ++nt)
                #pragma unroll
                for (int r = 0; r < 4; ++r)
                    comb[wg - 1][(wq * 32 + qh * 16 + quad * 4 + r) * 64 + nt * 16 + q16]
                        = o_acc[qh][nt][r];
    }
    if constexpr (MODE == 0) {
        // stage next-layer weights into psbuf[0..12288) (all 512 threads)
        const int wrow = tid >> 3, wch = tid & 7;
        alignas(16) ushort_t tw[8];
        const float* wsrc[3] = { qw, kw, vw };
        #pragma unroll
        for (int m = 0; m < 3; ++m) {
            #pragma unroll
            for (int i = 0; i < 8; ++i)
                tw[i] = f2bf(wsrc[m][(wch * 8 + i) * 64 + wrow]);
            *(short8*)&psbuf[m * 4096 + SW(wrow, wch)] = *(short8*)tw;
        }
    }
    __syncthreads();
    ushort_t* ot = &psbuf[3 * 4096];
    float pdot = 0.f;
    if (wg == 0) {
        #pragma unroll
        for (int qh = 0; qh < 2; ++qh) {
            float linv[4];
            #pragma unroll
            for (int r = 0; r < 4; ++r) {
                int ql = wq * 32 + qh * 16 + quad * 4 + r;
                linv[r] = 1.f / (lrow[0][ql] + lrow[1][ql] + lrow[2][ql] + lrow[3][ql]);
            }
            #pragma unroll
            for (int nt = 0; nt < 4; ++nt)
                #pragma unroll
                for (int r = 0; r < 4; ++r) {
                    int ql = wq * 32 + qh * 16 + quad * 4 + r;
                    int col = nt * 16 + q16;
                    float v = (o_acc[qh][nt][r] + comb[0][ql * 64 + col]
                               + comb[1][ql * 64 + col] + comb[2][ql * 64 + col]) * linv[r];
                    if constexpr (MODE == 1)
                        pdot += v * coeffs[(size_t)(q0 + ql) * EMB + col];
                    else
                        ot[SWE(ql, col)] = f2bf(v);
                }
        }
    }
    if constexpr (MODE == 1) {
        if (wg == 0) {
            #pragma unroll
            for (int off = 1; off < 64; off <<= 1) pdot += __shfl_xor(pdot, off);
            if (l == 0) atomicAdd(&out[b], pdot);
        }
        return;
    } else {
        __syncthreads();
        // next-layer QKV: waves 0-3 -> Q,K rows (w&3)*16; waves 4-7 -> V
        const int erow = (w & 3) * 16;
        floatx4 ra[4], rb[4];
        #pragma unroll
        for (int i = 0; i < 4; ++i) {
            ra[i] = (floatx4){0.f, 0.f, 0.f, 0.f};
            rb[i] = ra[i];
        }
        const ushort_t* wb0 = (w < 4) ? &psbuf[0] : &psbuf[2 * 4096];
        #pragma unroll
        for (int ksp = 0; ksp < 2; ++ksp) {
            short8 a = *(short8*)&ot[SW(erow + q16, ksp * 4 + quad)];
            #pragma unroll
            for (int nt = 0; nt < 4; ++nt) {
                int bo = SW(nt * 16 + q16, ksp * 4 + quad);
                ra[nt] = __builtin_amdgcn_mfma_f32_16x16x32_bf16(a, *(short8*)&wb0[bo], ra[nt], 0, 0, 0);
                if (w < 4)
                    rb[nt] = __builtin_amdgcn_mfma_f32_16x16x32_bf16(a, *(short8*)&psbuf[4096 + bo], rb[nt], 0, 0, 0);
            }
        }
        #pragma unroll
        for (int nt = 0; nt < 4; ++nt)
            #pragma unroll
            for (int r = 0; r < 4; ++r) {
                int row = q0 + erow + quad * 4 + r;   // within batch
                int col = nt * 16 + q16;
                if (w < 4) {
                    Qo[base + (size_t)row * EMB + col] = f2bf(ra[nt][r]);
                    Ko[base + (size_t)row * EMB + col] = f2bf(rb[nt][r]);
                } else {
                    Vo[vbase + (size_t)col * SEQ + row] = f2bf(ra[nt][r]);
                }
            }
    }
}

// ---------------------------------------------------------------------------
extern "C" void kernel_launch(void* const* d_in, const int* in_sizes, int n_in,
                              void* d_out, int out_size, void* d_ws, size_t ws_size,
                              hipStream_t stream) {
    const float* x      = (const float*)d_in[0];
    const float* q_ws   = (const float*)d_in[1];
    const float* k_ws   = (const float*)d_in[2];
    const float* v_ws   = (const float*)d_in[3];
    const float* rm     = (const float*)d_in[4];
    const float* coeffs = (const float*)d_in[5];
    const float* offset = (const float*)d_in[6];
    float* out = (float*)d_out;
    char* ws = (char*)d_ws;

    const size_t MB = 1024 * 1024;
    ushort_t* QbA = (ushort_t*)(ws + 0 * MB);
    ushort_t* KbA = (ushort_t*)(ws + 2 * MB);
    ushort_t* VtA = (ushort_t*)(ws + 4 * MB);
    ushort_t* QbB = (ushort_t*)(ws + 6 * MB);
    ushort_t* KbB = (ushort_t*)(ws + 8 * MB);
    ushort_t* VtB = (ushort_t*)(ws + 10 * MB);
    ushort_t* rmT = (ushort_t*)(ws + 12 * MB);

    prep_rmt<<<256, 256, 0, stream>>>(rm, rmT, out, offset);
    proj_qkv<<<256, 512, 0, stream>>>(x, rmT, q_ws, k_ws, v_ws, QbA, KbA, VtA);
    flash_fused<0><<<dim3(64, NB), 512, 0, stream>>>(QbA, KbA, VtA,
        q_ws + 4096, k_ws + 4096, v_ws + 4096, QbB, KbB, VtB, nullptr, nullptr);
    flash_fused<0><<<dim3(64, NB), 512, 0, stream>>>(QbB, KbB, VtB,
        q_ws + 8192, k_ws + 8192, v_ws + 8192, QbA, KbA, VtA, nullptr, nullptr);
    flash_fused<1><<<dim3(64, NB), 512, 0, stream>>>(QbA, KbA, VtA,
        nullptr, nullptr, nullptr, nullptr, nullptr, nullptr, coeffs, out);
}